// Round 5
// baseline (70.061 us; speedup 1.0000x reference)
//
#include <hip/hip_runtime.h>

// RBF layer: out[b,n] = exp(-GAMMA * (||x_b||^2 + ||w_n||^2 - 2 x_b . w_n))
// Two kernels:
//  1) prep: x(fp32)->x_bf16 + ||x||^2 ; W(fp32)->WT_bf16 (transposed) + ||w||^2
//  2) main: pure-register bf16 MFMA GEMM — NO LDS, NO barriers. Every fragment
//     is one global_load_dwordx4 from k-contiguous bf16 (L2-resident via
//     XCD-chunked swizzle). Fused exp2 epilogue.

#define GAMMA 0.5f
#define B_  4096
#define D_  256
#define N_  512

typedef __attribute__((ext_vector_type(8))) short bf16x8;
typedef __attribute__((ext_vector_type(4))) float f32x4;
typedef __attribute__((ext_vector_type(4))) float float4v;

__device__ __forceinline__ unsigned short f2bf(float f) {
    union { float f; unsigned int i; } u; u.f = f;
    return (unsigned short)(u.i >> 16);
}

// ---- kernel 1: prep (72 blocks x 256) ----
// blocks 0..63 : x rows -> x_bf16 + x2   (4 threads/row, 64 rows/block)
// blocks 64..71: W cols -> WT_bf16 + w2  (4 threads/col, 64 cols/block)
__global__ __launch_bounds__(256)
void rbf_prep(const float* __restrict__ x, const float* __restrict__ W,
              unsigned short* __restrict__ xbf, unsigned short* __restrict__ wt,
              float* __restrict__ x2, float* __restrict__ w2) {
    const int bid = blockIdx.x, tid = threadIdx.x;
    const int q = tid & 3;
    if (bid < 64) {
        const int row = bid * 64 + (tid >> 2);
        const float* xp = x + (size_t)row * D_ + q * 64;
        unsigned short* op = xbf + (size_t)row * D_ + q * 64;
        float s = 0.f;
        #pragma unroll
        for (int c = 0; c < 8; ++c) {
            float4v v0 = *(const float4v*)(xp + c * 8);
            float4v v1 = *(const float4v*)(xp + c * 8 + 4);
            s += v0.x*v0.x + v0.y*v0.y + v0.z*v0.z + v0.w*v0.w;
            s += v1.x*v1.x + v1.y*v1.y + v1.z*v1.z + v1.w*v1.w;
            bf16x8 o = { (short)f2bf(v0.x), (short)f2bf(v0.y), (short)f2bf(v0.z), (short)f2bf(v0.w),
                         (short)f2bf(v1.x), (short)f2bf(v1.y), (short)f2bf(v1.z), (short)f2bf(v1.w) };
            *(bf16x8*)(op + c * 8) = o;
        }
        s += __shfl_xor(s, 1); s += __shfl_xor(s, 2);
        if (q == 0) x2[row] = s;
    } else {
        const int n = (bid - 64) * 64 + (tid >> 2);
        const float* wp = W + (size_t)(q * 64) * N_ + n;   // walk down column n
        unsigned short* op = wt + (size_t)n * D_ + q * 64; // WT[n][k], k-contig
        float s = 0.f;
        #pragma unroll
        for (int c = 0; c < 8; ++c) {
            bf16x8 o;
            #pragma unroll
            for (int j = 0; j < 8; ++j) {
                float f = wp[(size_t)(c * 8 + j) * N_];
                s += f * f;
                o[j] = (short)f2bf(f);
            }
            *(bf16x8*)(op + c * 8) = o;
        }
        s += __shfl_xor(s, 1); s += __shfl_xor(s, 2);
        if (q == 0) w2[n] = s;
    }
}

// ---- kernel 2: main GEMM — no LDS, no barriers ----
// 512 blocks x 256: block = 64x64 tile, 2x2 waves, wave = 32x32 (2x2 frags).
__global__ __launch_bounds__(256, 2)
void rbf_main(const unsigned short* __restrict__ xbf, const unsigned short* __restrict__ wt,
              const float* __restrict__ x2, const float* __restrict__ w2,
              float* __restrict__ out) {
    const int tid = threadIdx.x, bid = blockIdx.x;
    // XCD-chunked bijective swizzle (512 % 8 == 0)
    const int wgid = (bid & 7) * 64 + (bid >> 3);
    const int bx = wgid & 7;    // col tile (bx*64)
    const int by = wgid >> 3;   // row tile (by*64)

    const int l = tid & 63, w = tid >> 6;
    const int wr = w >> 1, wc = w & 1;
    const int lr = l & 15, g = l >> 4;

    // A frag: lane holds x[row=..+lr][k=g*8+j]; B frag: WT[col=..+lr][k=g*8+j]
    const unsigned short* ap0 = xbf + (size_t)(by * 64 + wr * 32 + lr) * D_ + g * 8;
    const unsigned short* ap1 = ap0 + 16 * D_;
    const unsigned short* bp0 = wt + (size_t)(bx * 64 + wc * 32 + lr) * D_ + g * 8;
    const unsigned short* bp1 = bp0 + 16 * D_;

    f32x4 acc[2][2] = {{{0,0,0,0},{0,0,0,0}},{{0,0,0,0},{0,0,0,0}}};
    #pragma unroll
    for (int kk = 0; kk < 8; ++kk) {
        bf16x8 a0 = *(const bf16x8*)(ap0 + kk * 32);
        bf16x8 a1 = *(const bf16x8*)(ap1 + kk * 32);
        bf16x8 b0 = *(const bf16x8*)(bp0 + kk * 32);
        bf16x8 b1 = *(const bf16x8*)(bp1 + kk * 32);
        acc[0][0] = __builtin_amdgcn_mfma_f32_16x16x32_bf16(a0, b0, acc[0][0], 0, 0, 0);
        acc[0][1] = __builtin_amdgcn_mfma_f32_16x16x32_bf16(a0, b1, acc[0][1], 0, 0, 0);
        acc[1][0] = __builtin_amdgcn_mfma_f32_16x16x32_bf16(a1, b0, acc[1][0], 0, 0, 0);
        acc[1][1] = __builtin_amdgcn_mfma_f32_16x16x32_bf16(a1, b1, acc[1][1], 0, 0, 0);
    }

    // epilogue: C/D layout col=lane&15, row=(lane>>4)*4+i (m89/m91)
    const float c2l = -(GAMMA) * 1.4426950408889634f;
    float* outp = out + (size_t)(by * 64) * N_ + bx * 64;
    #pragma unroll
    for (int m = 0; m < 2; ++m) {
        #pragma unroll
        for (int n = 0; n < 2; ++n) {
            const int ac = wc * 32 + n * 16 + lr;
            const float w2v = w2[bx * 64 + ac];
            #pragma unroll
            for (int i = 0; i < 4; ++i) {
                const int ar = wr * 32 + m * 16 + g * 4 + i;
                const float s = x2[by * 64 + ar] + w2v - 2.f * acc[m][n][i];
                outp[(size_t)ar * N_ + ac] = exp2f(s * c2l);
            }
        }
    }
}

extern "C" void kernel_launch(void* const* d_in, const int* in_sizes, int n_in,
                              void* d_out, int out_size, void* d_ws, size_t ws_size,
                              hipStream_t stream) {
    const float* x = (const float*)d_in[0];
    const float* W = (const float*)d_in[1];
    float* out = (float*)d_out;

    char* ws = (char*)d_ws;
    unsigned short* xbf = (unsigned short*)(ws);                      // 2 MiB
    unsigned short* wt  = (unsigned short*)(ws + (2u << 20));         // 256 KiB
    float* x2 = (float*)(ws + (3u << 20));                            // 16 KiB
    float* w2 = (float*)(ws + (3u << 20) + (64u << 10));              // 2 KiB

    rbf_prep<<<dim3(72), dim3(256), 0, stream>>>(x, W, xbf, wt, x2, w2);
    rbf_main<<<dim3(512), dim3(256), 0, stream>>>(xbf, wt, x2, w2, out);
}

// Round 6
// 64.083 us; speedup vs baseline: 1.0933x; 1.0933x over previous
//
#include <hip/hip_runtime.h>

// RBF layer: out[b,n] = exp(-GAMMA * (||x_b||^2 + ||w_n||^2 - 2 x_b . w_n))
// x: (4096,256) fp32; W: (256,512) fp32; out: (4096,512) fp32.
// Single kernel, single barrier:
//   stage x->bf16 LDS with ||x||^2 accumulated in-register during the load
//   -> __syncthreads -> MFMA main loop (W fp32 global->reg, L2-hot, ||w||^2
//   in-register) -> fused exp2 epilogue. No d_ws use (stays parallel to the
//   harness ws-poison fill). XCD-chunked block swizzle.

#define GAMMA 0.5f
#define B_  4096
#define D_  256
#define N_  512
#define BM  64
#define BN  64
#define LDT 264   // 256 + 8 pad (bf16): 528B row stride

typedef __attribute__((ext_vector_type(8))) short bf16x8;
typedef __attribute__((ext_vector_type(4))) float f32x4;
typedef __attribute__((ext_vector_type(4))) float float4v;

__device__ __forceinline__ unsigned short f2bf(float f) {
    union { float f; unsigned int i; } u; u.f = f;
    return (unsigned short)(u.i >> 16);
}

__global__ __launch_bounds__(256, 2)
void rbf_kernel(const float* __restrict__ x, const float* __restrict__ W,
                float* __restrict__ out) {
    __shared__ unsigned short xs[BM][LDT];   // x tile, bf16
    __shared__ float x2s[BM];

    const int tid = threadIdx.x;

    // XCD-chunked bijective swizzle (512 % 8 == 0): XCD k owns by in [8k,8k+8)
    const int bid = blockIdx.x;
    const int wgid = (bid & 7) * 64 + (bid >> 3);
    const int bx = wgid & 7;    // 0..7
    const int by = wgid >> 3;   // 0..63

    // ---- merged stage + norm: thread (row, q) owns 64 floats of one row ----
    {
        const int row = tid >> 2, q = tid & 3;
        const float* xp = x + (size_t)(by * BM + row) * D_ + q * 64;
        unsigned short* lp = &xs[row][q * 64];
        float s = 0.f;
        #pragma unroll
        for (int c = 0; c < 8; ++c) {
            float4v v0 = *(const float4v*)(xp + c * 8);
            float4v v1 = *(const float4v*)(xp + c * 8 + 4);
            s += v0.x*v0.x + v0.y*v0.y + v0.z*v0.z + v0.w*v0.w
               + v1.x*v1.x + v1.y*v1.y + v1.z*v1.z + v1.w*v1.w;
            bf16x8 o = { (short)f2bf(v0.x), (short)f2bf(v0.y), (short)f2bf(v0.z), (short)f2bf(v0.w),
                         (short)f2bf(v1.x), (short)f2bf(v1.y), (short)f2bf(v1.z), (short)f2bf(v1.w) };
            *(bf16x8*)(lp + c * 8) = o;
        }
        s += __shfl_xor(s, 1);
        s += __shfl_xor(s, 2);
        if (q == 0) x2s[row] = s;
    }
    __syncthreads();   // the only barrier

    // ---- MFMA: 2x2 waves, each 32x32; A from LDS, B fp32 global (L2-hot) ----
    const int l = tid & 63, w = tid >> 6;
    const int wr = w >> 1, wc = w & 1;
    const int lr = l & 15, g = l >> 4;

    const float* Wg = W + bx * BN + wc * 32 + lr;
    float w2p0 = 0.f, w2p1 = 0.f;
    f32x4 acc[2][2] = {{{0,0,0,0},{0,0,0,0}},{{0,0,0,0},{0,0,0,0}}};

    #pragma unroll
    for (int kk = 0; kk < 8; ++kk) {
        const int k0 = kk * 32 + g * 8;
        const float* wp = Wg + (size_t)k0 * N_;
        float w0[8], w1[8];
        #pragma unroll
        for (int j = 0; j < 8; ++j) {
            w0[j] = wp[(size_t)j * N_];
            w1[j] = wp[(size_t)j * N_ + 16];
        }
        bf16x8 b0, b1;
        #pragma unroll
        for (int j = 0; j < 8; ++j) {
            b0[j] = (short)f2bf(w0[j]); b1[j] = (short)f2bf(w1[j]);
            w2p0 += w0[j] * w0[j];      w2p1 += w1[j] * w1[j];
        }
        bf16x8 a0 = *(const bf16x8*)&xs[wr * 32 + lr][k0];
        bf16x8 a1 = *(const bf16x8*)&xs[wr * 32 + 16 + lr][k0];
        acc[0][0] = __builtin_amdgcn_mfma_f32_16x16x32_bf16(a0, b0, acc[0][0], 0, 0, 0);
        acc[0][1] = __builtin_amdgcn_mfma_f32_16x16x32_bf16(a0, b1, acc[0][1], 0, 0, 0);
        acc[1][0] = __builtin_amdgcn_mfma_f32_16x16x32_bf16(a1, b0, acc[1][0], 0, 0, 0);
        acc[1][1] = __builtin_amdgcn_mfma_f32_16x16x32_bf16(a1, b1, acc[1][1], 0, 0, 0);
    }

    // w2 partials: lane (g) covered k in [g*8, g*8+8) mod 32 -> reduce over g
    w2p0 += __shfl_xor(w2p0, 16); w2p0 += __shfl_xor(w2p0, 32);
    w2p1 += __shfl_xor(w2p1, 16); w2p1 += __shfl_xor(w2p1, 32);

    // ---- epilogue: C/D layout col=lane&15, row=(lane>>4)*4+i (m89/m91) ----
    const float c2l = -(GAMMA) * 1.4426950408889634f;
    float* outp = out + (size_t)(by * BM) * N_ + bx * BN;
    #pragma unroll
    for (int m = 0; m < 2; ++m) {
        #pragma unroll
        for (int n = 0; n < 2; ++n) {
            const int ac = wc * 32 + n * 16 + lr;
            const float w2v = n ? w2p1 : w2p0;
            #pragma unroll
            for (int i = 0; i < 4; ++i) {
                const int ar = wr * 32 + m * 16 + g * 4 + i;
                const float s = x2s[ar] + w2v - 2.f * acc[m][n][i];
                outp[(size_t)ar * N_ + ac] = exp2f(s * c2l);
            }
        }
    }
}

extern "C" void kernel_launch(void* const* d_in, const int* in_sizes, int n_in,
                              void* d_out, int out_size, void* d_ws, size_t ws_size,
                              hipStream_t stream) {
    const float* x = (const float*)d_in[0];
    const float* W = (const float*)d_in[1];
    float* out = (float*)d_out;
    rbf_kernel<<<dim3(512), dim3(256), 0, stream>>>(x, W, out);
}